// Round 1
// 88.962 us; speedup vs baseline: 1.0073x; 1.0073x over previous
//
#include <hip/hip_runtime.h>
#include <hip/hip_bf16.h>

// Problem constants (from reference):
#define B 4
#define N 256
#define F 128
#define H 256
// OUT = 1

// ---------------------------------------------------------------------------
// kAW: A[b,i,h] = relu(x[b,i,:]) @ W1[F:2F, :]      (NO ub term -- deferred)
//      W[b,j,h] = relu(x[b,j,:]) @ W1[2F:3F, :]
// grid = B*N/2 = 512 blocks (2 rows each), block = 256 (thread = h).
// Blocks 0..B-1 ALSO compute the pooled path for batch==blockIdx.x:
//      ub[b,h] = b1[h] + relu((mean_i x[b,i,:]) @ Wp) @ W1[0:F, :]
// (unchanged this round -- isolating the kPair rewrite)
// ---------------------------------------------------------------------------
__global__ __launch_bounds__(256) void kAW(
    const float* __restrict__ x, const float* __restrict__ Wp,
    const float* __restrict__ W1, const float* __restrict__ b1,
    float* __restrict__ ub, float* __restrict__ A, float* __restrict__ W) {
  __shared__ float xr[2][F];
  const int blk = blockIdx.x;
  const int b = blk >> 7;            // 128 blocks per batch
  const int i0 = (blk & 127) * 2;
  const int t = threadIdx.x;         // h

  // stage 2 relu'd input rows (256 floats -> one per thread)
  {
    const int r = t >> 7, f = t & 127;
    xr[r][f] = fmaxf(x[(b * N + i0 + r) * F + f], 0.f);
  }
  __syncthreads();

  float a0 = 0.f, a1 = 0.f, w0 = 0.f, w1 = 0.f;
  const float* W1i = W1 + F * H;       // rows F..2F-1
  const float* W1j = W1 + 2 * F * H;   // rows 2F..3F-1
#pragma unroll 8
  for (int f = 0; f < F; ++f) {
    const float wi = W1i[f * H + t];
    const float wj = W1j[f * H + t];
    const float x0 = xr[0][f];
    const float x1 = xr[1][f];
    a0 = fmaf(x0, wi, a0);
    a1 = fmaf(x1, wi, a1);
    w0 = fmaf(x0, wj, w0);
    w1 = fmaf(x1, wj, w1);
  }
  A[(b * N + i0) * H + t] = a0;
  A[(b * N + i0 + 1) * H + t] = a1;
  W[(b * N + i0) * H + t] = w0;
  W[(b * N + i0 + 1) * H + t] = w1;

  // ---- pooled path: 4 of 512 blocks, batch pb = blk (uniform branch) ----
  if (blk < B) {
    __shared__ float4 red4[256];
    __shared__ float xm_s[F];
    __shared__ float rp_s[F];
    __shared__ float part[256];
    const int pb = blk;
    const float4* xb4 = (const float4*)(x + pb * N * F);
    float4 acc = make_float4(0.f, 0.f, 0.f, 0.f);
#pragma unroll 8
    for (int k = 0; k < 32; ++k) {  // 8192 float4 total; col-group = t & 31
      const float4 v = xb4[t + 256 * k];
      acc.x += v.x; acc.y += v.y; acc.z += v.z; acc.w += v.w;
    }
    red4[t] = acc;
    __syncthreads();
    if (t < 32) {
      float4 s = red4[t];
#pragma unroll
      for (int m = 1; m < 8; ++m) {
        const float4 v = red4[t + 32 * m];
        s.x += v.x; s.y += v.y; s.z += v.z; s.w += v.w;
      }
      const float inv = 1.f / (float)N;
      xm_s[4 * t + 0] = s.x * inv;
      xm_s[4 * t + 1] = s.y * inv;
      xm_s[4 * t + 2] = s.z * inv;
      xm_s[4 * t + 3] = s.w * inv;
    }
    __syncthreads();
    // rp = relu(xm @ Wp): 2 threads per output, 64 MACs each
    {
      const int lo = t & 127, kh = t >> 7;
      float p = 0.f;
      const int k0 = kh * 64;
#pragma unroll 8
      for (int kk = 0; kk < 64; ++kk) {
        const int k = k0 + kk;
        p = fmaf(xm_s[k], Wp[k * F + lo], p);
      }
      part[t] = p;
    }
    __syncthreads();
    if (t < 128) rp_s[t] = fmaxf(part[t] + part[t + 128], 0.f);
    __syncthreads();
    // ub[pb, t] = b1[t] + rp @ W1[0:F, t]
    {
      float u = b1[t];
#pragma unroll 8
      for (int k = 0; k < F; ++k) u = fmaf(rp_s[k], W1[k * H + t], u);
      ub[pb * H + t] = u;
    }
  }
}

// ---------------------------------------------------------------------------
// kPair v2: out[b,i,j] = b2 + sum_h relu((A[b,i,h]+ub[b,h]) + W[b,j,h]) * W2[h]
// Tile 32i x 16j, FULL h=256 in-block. grid = (16,8,B) = 512 blocks, blk=256.
//
// CHANGE vs v1: LDS layout is h-CONTIGUOUS ([i][h], [j][h]) with row stride
// 260 floats (pad 4, keeps 16B alignment). Inner loop reads float4 over h:
// 4x ds_read_b128 per 4h per thread instead of 16x ds_read_b32 -> loop goes
// from LDS-issue-bound (~4 scalar reads/h/thread @ ~5.8cyc) to VALU-bound
// (3 VALU ops per output per h = the floor).
//
// Bank analysis (stride 260 words: 260 % 32 == 4):
//   a-read:  rows ti=0..7 per wave -> banks 4*(ti+hq) : 8 distinct groups of
//            4 banks tiling all 32 -> conflict-free b128.
//   w-reads: j mapped as (tj, tj+8); 260*8 == 2080 == 65*32 -> both reads hit
//            the same conflict-free pattern as a-read.
//   w2-read: uniform address -> broadcast, free.
//   staging writes: one full contiguous 1KB row per wave -> all 32 banks
//            fully utilized (mandatory BW, no wasted conflicts).
// LDS: 32*260*4 + 16*260*4 + 1KB = 50.9 KB -> 2 blocks/CU (grid-limited).
// ---------------------------------------------------------------------------
#define SROW 65   // row stride in float4 units (260 floats = 1040 B, 16B-aligned)
__global__ __launch_bounds__(256) void kPair(
    const float* __restrict__ A, const float* __restrict__ W,
    const float* __restrict__ ub, const float* __restrict__ W2,
    const float* __restrict__ b2, float* __restrict__ out) {
  __shared__ float4 aS[32 * SROW];  // [i][h/4], ub folded in
  __shared__ float4 wS[16 * SROW];  // [j][h/4]
  __shared__ float4 w2s[64];        // [h/4]

  const int b = blockIdx.z;
  const int i0 = blockIdx.y * 32;
  const int j0 = blockIdx.x * 16;
  const int t = threadIdx.x;

  const int c = t & 63;    // float4 column (h/4)
  const int rp = t >> 6;   // 0..3 : row phase

  if (t < 64) w2s[t] = ((const float4*)W2)[t];

  // ub folded into aS during staging (loaded once per thread, reused 8x)
  const float4 ubv = ((const float4*)(ub + b * H))[c];

  const float4* A4 = (const float4*)(A + (size_t)(b * N + i0) * H);
#pragma unroll
  for (int p = 0; p < 8; ++p) {
    const int r = rp + 4 * p;            // 0..31
    float4 v = A4[r * 64 + c];           // contiguous 1KB per wave (L2-hot)
    v.x += ubv.x; v.y += ubv.y; v.z += ubv.z; v.w += ubv.w;
    aS[r * SROW + c] = v;                // contiguous row write: full LDS BW
  }
  const float4* W4 = (const float4*)(W + (size_t)(b * N + j0) * H);
#pragma unroll
  for (int p = 0; p < 4; ++p) {
    const int r = rp + 4 * p;            // 0..15
    wS[r * SROW + c] = W4[r * 64 + c];
  }
  __syncthreads();

  const int ti = t >> 3;   // i-row 0..31
  const int tj = t & 7;    // j-half-index: handles j0+tj and j0+tj+8
  const float4* ap  = aS + ti * SROW;
  const float4* wp0 = wS + tj * SROW;
  const float4* wp1 = wS + (tj + 8) * SROW;

  float acc0 = 0.f, acc1 = 0.f;
#pragma unroll 4
  for (int hq = 0; hq < 64; ++hq) {
    const float4 av = ap[hq];
    const float4 w0 = wp0[hq];
    const float4 w1 = wp1[hq];
    const float4 w2 = w2s[hq];
    acc0 = fmaf(fmaxf(av.x + w0.x, 0.f), w2.x, acc0);
    acc0 = fmaf(fmaxf(av.y + w0.y, 0.f), w2.y, acc0);
    acc0 = fmaf(fmaxf(av.z + w0.z, 0.f), w2.z, acc0);
    acc0 = fmaf(fmaxf(av.w + w0.w, 0.f), w2.w, acc0);
    acc1 = fmaf(fmaxf(av.x + w1.x, 0.f), w2.x, acc1);
    acc1 = fmaf(fmaxf(av.y + w1.y, 0.f), w2.y, acc1);
    acc1 = fmaf(fmaxf(av.z + w1.z, 0.f), w2.z, acc1);
    acc1 = fmaf(fmaxf(av.w + w1.w, 0.f), w2.w, acc1);
  }

  const float bb = b2[0];
  float* o = out + (size_t)(b * N + i0 + ti) * N + j0;
  o[tj] = acc0 + bb;
  o[tj + 8] = acc1 + bb;
}

extern "C" void kernel_launch(void* const* d_in, const int* in_sizes, int n_in,
                              void* d_out, int out_size, void* d_ws, size_t ws_size,
                              hipStream_t stream) {
  const float* x  = (const float*)d_in[0];  // [B,N,F]
  const float* Wp = (const float*)d_in[1];  // [F,F]
  const float* W1 = (const float*)d_in[2];  // [3F,H]
  const float* b1 = (const float*)d_in[3];  // [H]
  const float* W2 = (const float*)d_in[4];  // [H,1]
  const float* b2 = (const float*)d_in[5];  // [1]
  float* out = (float*)d_out;               // [B,N,N,1]

  float* ws = (float*)d_ws;
  float* ub = ws;                  // B*H   = 1024
  float* A  = ub + B * H;          // B*N*H = 262144
  float* W  = A + B * N * H;       // B*N*H = 262144
  // total: 525312 floats = 2.1 MB of d_ws; every element written before read

  kAW<<<dim3(B * N / 2), dim3(256), 0, stream>>>(x, Wp, W1, b1, ub, A, W);
  kPair<<<dim3(N / 16, N / 32, B), dim3(256), 0, stream>>>(A, W, ub, W2, b2, out);
}